// Round 2
// baseline (1133.155 us; speedup 1.0000x reference)
//
#include <hip/hip_runtime.h>
#include <math.h>

#define U_DIM 8192
#define P_DIM 4096
#define B_DIM 1024
#define H_DIM 50
#define EPSV  1e-8f

typedef __attribute__((ext_vector_type(8))) short short8;
typedef __attribute__((ext_vector_type(4))) short short4v;
typedef __attribute__((ext_vector_type(2))) short short2v;
typedef __attribute__((ext_vector_type(4))) float f32x4;

struct APtrs { const float* p[5]; };

__device__ inline unsigned short f2bf(float f) {
    unsigned int u = __float_as_uint(f);
    u += 0x7FFFu + ((u >> 16) & 1u);
    return (unsigned short)(u >> 16);
}

// ---------------------------------------------------------------------------
// One-time A conversion: fp32 [8192][4096] -> bf16 row-major AND (optionally)
// bf16 transposed [4096][8192]. Fully coalesced reads and writes (LDS-tiled
// transpose). This removes fp32 A traffic + per-use f2bf from all GEMMs.
__global__ __launch_bounds__(256) void conv_bf16_k(
    APtrs Aps, unsigned short* __restrict__ rm, unsigned short* __restrict__ tp)
{
    __shared__ float t[64][65];
    const int tid = threadIdx.x;
    const int p0 = blockIdx.x * 64;     // col tile (P dim)
    const int m0 = blockIdx.y * 64;     // row tile (U dim)
    const size_t rbase = (size_t)blockIdx.z * ((size_t)U_DIM * P_DIM);
    const float* ip = Aps.p[blockIdx.z];
    unsigned short* rp = rm + rbase;
    const int c4 = (tid & 15) * 4;
#pragma unroll
    for (int j = 0; j < 4; ++j) {
        int row = (tid >> 4) + j * 16;
        float4 v = *(const float4*)(ip + (size_t)(m0 + row) * P_DIM + p0 + c4);
        short4v w = { (short)f2bf(v.x), (short)f2bf(v.y), (short)f2bf(v.z), (short)f2bf(v.w) };
        *(short4v*)(rp + (size_t)(m0 + row) * P_DIM + p0 + c4) = w;
        t[row][c4 + 0] = v.x; t[row][c4 + 1] = v.y;
        t[row][c4 + 2] = v.z; t[row][c4 + 3] = v.w;
    }
    if (!tp) return;
    __syncthreads();
    unsigned short* op = tp + rbase;
#pragma unroll
    for (int j = 0; j < 4; ++j) {
        int prow = (tid >> 4) + j * 16;
        short4v w = { (short)f2bf(t[c4 + 0][prow]), (short)f2bf(t[c4 + 1][prow]),
                      (short)f2bf(t[c4 + 2][prow]), (short)f2bf(t[c4 + 3][prow]) };
        *(short4v*)(op + (size_t)(p0 + prow) * U_DIM + m0 + c4) = w;
    }
}

// ---------------------------------------------------------------------------
// Transpose + bf16 convert for the SMALL B operands: in [K][64] fp32 ->
// out [64][K] bf16 (L2-resident, read as contiguous short8 by the GEMMs).
__global__ __launch_bounds__(256) void transpose_bf16_k(
    const float* __restrict__ in, unsigned short* __restrict__ out,
    int K, long strideIn, long strideOut)
{
    __shared__ float t[64][65];
    const int tid = threadIdx.x;
    const int kb  = blockIdx.x * 64;
    const float* ip = in + (size_t)blockIdx.y * strideIn + (size_t)kb * 64;
#pragma unroll
    for (int j = 0; j < 16; ++j) {
        int idx = tid + j * 256;
        t[idx >> 6][idx & 63] = ip[idx];
    }
    __syncthreads();
    unsigned short* op = out + (size_t)blockIdx.y * strideOut;
#pragma unroll
    for (int j = 0; j < 16; ++j) {
        int idx = tid + j * 256;
        int d = idx >> 6, k = idx & 63;
        op[(size_t)d * K + kb + k] = f2bf(t[k][d]);
    }
}

// ---------------------------------------------------------------------------
// C[M x 64] += A @ B with A bf16. LDS-free / barrier-free; A fragments are
// contiguous short8 global loads (each 64B line fully consumed by one
// instruction's 4 k-groups); B fragments contiguous short8 from the
// L2-resident transposed operand. Depth-1 ping-pong pipeline.
// TRANS=0: A' = Abase row-major [M][K] (tier A: used for ALL four GEMMs)
// TRANS=1: A'[p][k] = Abase[k*P_DIM + p]  (tier B only: scattered u16 loads)
template<bool TRANS>
__global__ __launch_bounds__(256, 4) void gemm_bf16(
    const unsigned short* __restrict__ Abase, long strideA,
    const unsigned short* __restrict__ BT, long strideBT,
    float* __restrict__ C, long strideC, int K, int kseg)
{
    const int tid  = threadIdx.x;
    const int wid  = tid >> 6;
    const int lane = tid & 63;
    const int l15  = lane & 15;
    const int kg   = (lane >> 4) << 3;          // k-group offset 0/8/16/24
    const int m0   = blockIdx.x * 128 + wid * 32;
    const unsigned short* A  = Abase + (size_t)blockIdx.y * strideA;
    const unsigned short* Bp = BT + (size_t)blockIdx.y * strideBT;
    float* Cp = C + (size_t)blockIdx.y * strideC;
    const long k0 = (long)blockIdx.z * kseg + kg;

    const unsigned short* a0;
    if (!TRANS) a0 = A + (size_t)(m0 + l15) * K + k0;
    else        a0 = A + (size_t)k0 * P_DIM + m0 + l15;
    const unsigned short* b0 = Bp + (size_t)l15 * K + k0;
    const size_t aK16 = (size_t)16 * K;

    f32x4 acc[2][4] = {};
    short8 Aa[2], Ab[2], Ba[4], Bb[4];

#define LA(R_, kk_) do {                                                        \
    if (!TRANS) {                                                               \
        R_[0] = *(const short8*)(a0 + (kk_));                                   \
        R_[1] = *(const short8*)(a0 + aK16 + (kk_));                            \
    } else {                                                                    \
        _Pragma("unroll")                                                       \
        for (int j = 0; j < 8; ++j) {                                           \
            R_[0][j] = (short)a0[(size_t)((kk_) + j) * P_DIM];                  \
            R_[1][j] = (short)a0[(size_t)((kk_) + j) * P_DIM + 16];             \
        }                                                                       \
    }                                                                           \
} while (0)

#define LB(R_, kk_) do {                                                        \
    R_[0] = *(const short8*)(b0 + (kk_));                                       \
    R_[1] = *(const short8*)(b0 + aK16 + (kk_));                                \
    R_[2] = *(const short8*)(b0 + 2 * aK16 + (kk_));                            \
    R_[3] = *(const short8*)(b0 + 3 * aK16 + (kk_));                            \
} while (0)

#define STEP(A_, B_) do {                                                       \
    _Pragma("unroll")                                                           \
    for (int nt = 0; nt < 4; ++nt) {                                            \
        acc[0][nt] = __builtin_amdgcn_mfma_f32_16x16x32_bf16(A_[0], B_[nt], acc[0][nt], 0, 0, 0); \
        acc[1][nt] = __builtin_amdgcn_mfma_f32_16x16x32_bf16(A_[1], B_[nt], acc[1][nt], 0, 0, 0); \
    }                                                                           \
} while (0)

    LA(Aa, 0); LB(Ba, 0);
    for (int kk = 0; kk < kseg; kk += 64) {
        LA(Ab, kk + 32); LB(Bb, kk + 32);
        STEP(Aa, Ba);
        if (kk + 64 < kseg) { LA(Aa, kk + 64); LB(Ba, kk + 64); }
        STEP(Ab, Bb);
    }

#undef LA
#undef LB
#undef STEP

    const int rb4 = (lane >> 4) << 2;
#pragma unroll
    for (int mt = 0; mt < 2; ++mt)
#pragma unroll
        for (int nt = 0; nt < 4; ++nt)
#pragma unroll
            for (int i = 0; i < 4; ++i) {
                int row = m0 + (mt << 4) + rb4 + i;
                atomicAdd(&Cp[((size_t)row << 6) + (nt << 4) + l15], acc[mt][nt][i]);
            }
}

// ---------------------------------------------------------------------------
// Tier-C emergency fallback (ws too small for bf16 copies): fp32 LDS-free
// GEMM — exact proven round-1 code.
template<bool TRANS>
__global__ __launch_bounds__(256, 4) void gemm_f32(
    APtrs Aps, const unsigned short* __restrict__ BT, float* __restrict__ C,
    long strideBT, long strideC, int kseg)
{
    const int K   = TRANS ? U_DIM : P_DIM;
    const int tid  = threadIdx.x;
    const int wid  = tid >> 6;
    const int lane = tid & 63;
    const int l15  = lane & 15;
    const int kg   = (lane >> 4) << 3;
    const int m0   = blockIdx.x * 128 + wid * 32;
    const float* Ag = Aps.p[blockIdx.y];
    const unsigned short* Bp = BT + (size_t)blockIdx.y * strideBT;
    float* Cp = C + (size_t)blockIdx.y * strideC;
    const long k0 = (long)blockIdx.z * kseg + kg;

    const float* a0;
    if (!TRANS) a0 = Ag + (size_t)(m0 + l15) * K + k0;
    else        a0 = Ag + (size_t)k0 * P_DIM + m0 + l15;
    const unsigned short* b0 = Bp + (size_t)l15 * K + k0;
    const size_t a16 = (size_t)16 * K;
    const size_t K16 = (size_t)16 * K;

    f32x4 acc[2][4] = {};

#define LOADA(A_, kk_) do {                                                     \
    if (!TRANS) {                                                               \
        const float* ap_ = a0 + (kk_);                                          \
        A_[0] = *(const float4*)ap_;          A_[1] = *(const float4*)(ap_ + 4);\
        A_[2] = *(const float4*)(ap_ + a16);  A_[3] = *(const float4*)(ap_ + a16 + 4); \
    } else {                                                                    \
        const float* ap_ = a0 + (size_t)(kk_) * P_DIM;                          \
        A_[0].x = ap_[0 * (size_t)P_DIM];      A_[0].y = ap_[1 * (size_t)P_DIM];\
        A_[0].z = ap_[2 * (size_t)P_DIM];      A_[0].w = ap_[3 * (size_t)P_DIM];\
        A_[1].x = ap_[4 * (size_t)P_DIM];      A_[1].y = ap_[5 * (size_t)P_DIM];\
        A_[1].z = ap_[6 * (size_t)P_DIM];      A_[1].w = ap_[7 * (size_t)P_DIM];\
        A_[2].x = ap_[0 * (size_t)P_DIM + 16]; A_[2].y = ap_[1 * (size_t)P_DIM + 16]; \
        A_[2].z = ap_[2 * (size_t)P_DIM + 16]; A_[2].w = ap_[3 * (size_t)P_DIM + 16]; \
        A_[3].x = ap_[4 * (size_t)P_DIM + 16]; A_[3].y = ap_[5 * (size_t)P_DIM + 16]; \
        A_[3].z = ap_[6 * (size_t)P_DIM + 16]; A_[3].w = ap_[7 * (size_t)P_DIM + 16]; \
    }                                                                           \
} while (0)

#define LOADB(B_, kk_) do {                                                     \
    B_[0] = *(const short8*)(b0 + (kk_));                                       \
    B_[1] = *(const short8*)(b0 + K16 + (kk_));                                 \
    B_[2] = *(const short8*)(b0 + 2 * K16 + (kk_));                             \
    B_[3] = *(const short8*)(b0 + 3 * K16 + (kk_));                             \
} while (0)

#define STEPF(A_, B_) do {                                                      \
    short8 a0f, a1f;                                                            \
    a0f[0] = (short)f2bf(A_[0].x); a0f[1] = (short)f2bf(A_[0].y);               \
    a0f[2] = (short)f2bf(A_[0].z); a0f[3] = (short)f2bf(A_[0].w);               \
    a0f[4] = (short)f2bf(A_[1].x); a0f[5] = (short)f2bf(A_[1].y);               \
    a0f[6] = (short)f2bf(A_[1].z); a0f[7] = (short)f2bf(A_[1].w);               \
    a1f[0] = (short)f2bf(A_[2].x); a1f[1] = (short)f2bf(A_[2].y);               \
    a1f[2] = (short)f2bf(A_[2].z); a1f[3] = (short)f2bf(A_[2].w);               \
    a1f[4] = (short)f2bf(A_[3].x); a1f[5] = (short)f2bf(A_[3].y);               \
    a1f[6] = (short)f2bf(A_[3].z); a1f[7] = (short)f2bf(A_[3].w);               \
    _Pragma("unroll")                                                           \
    for (int nt = 0; nt < 4; ++nt) {                                            \
        acc[0][nt] = __builtin_amdgcn_mfma_f32_16x16x32_bf16(a0f, B_[nt], acc[0][nt], 0, 0, 0); \
        acc[1][nt] = __builtin_amdgcn_mfma_f32_16x16x32_bf16(a1f, B_[nt], acc[1][nt], 0, 0, 0); \
    }                                                                           \
} while (0)

    float4 Aa[4], Ab[4];
    short8 Ba[4], Bb[4];
    LOADA(Aa, 0); LOADB(Ba, 0);
    for (int kk = 0; kk < kseg; kk += 64) {
        LOADA(Ab, kk + 32); LOADB(Bb, kk + 32);
        STEPF(Aa, Ba);
        if (kk + 64 < kseg) { LOADA(Aa, kk + 64); LOADB(Ba, kk + 64); }
        STEPF(Ab, Bb);
    }

#undef LOADA
#undef LOADB
#undef STEPF

    const int rb4 = (lane >> 4) << 2;
#pragma unroll
    for (int mt = 0; mt < 2; ++mt)
#pragma unroll
        for (int nt = 0; nt < 4; ++nt)
#pragma unroll
            for (int i = 0; i < 4; ++i) {
                int row = m0 + (mt << 4) + rb4 + i;
                atomicAdd(&Cp[((size_t)row << 6) + (nt << 4) + l15], acc[mt][nt][i]);
            }
}

__device__ inline float wsum(float v) {
#pragma unroll
    for (int off = 32; off > 0; off >>= 1) v += __shfl_xor(v, off, 64);
    return v;
}

// One wave per user: Xu, cosine sims vs base, mask/var, user_embedding.
__global__ __launch_bounds__(256) void user_stats_k(
    const float* __restrict__ u0, const float* __restrict__ u1,
    const float* __restrict__ u2, const float* __restrict__ W,
    float* __restrict__ base_o, float* __restrict__ var_o, float* __restrict__ ue_o)
{
    int u    = blockIdx.x * 4 + (threadIdx.x >> 6);
    int lane = threadIdx.x & 63;
    size_t ud = ((size_t)u << 6) + lane;

    float b0 = u0[ud];
    float xu[5];
#pragma unroll
    for (int r = 0; r < 5; ++r)
        xu[r] = (b0 + u1[(size_t)r * U_DIM * 64 + ud] + u2[(size_t)r * U_DIM * 64 + ud]) * (1.0f / 3.0f);

    float base = xu[0];
    float n0 = sqrtf(wsum(base * base));
    float sim[4];
#pragma unroll
    for (int a = 0; a < 4; ++a) {
        float d  = wsum(base * xu[a + 1]);
        float nr = sqrtf(wsum(xu[a + 1] * xu[a + 1]));
        sim[a] = d / fmaxf(n0 * nr, EPSV);
    }
    float smax = fmaxf(fmaxf(sim[0], sim[1]), fmaxf(sim[2], sim[3]));
    float ssum = 0.0f;
    float simm[4];
#pragma unroll
    for (int a = 0; a < 4; ++a) { simm[a] = (sim[a] == smax) ? sim[a] : 0.0f; ssum += simm[a]; }
    float mean = ssum * 0.25f;
    float vs = 0.0f;
#pragma unroll
    for (int a = 0; a < 4; ++a) { float t = simm[a] - mean; vs += t * t; }
    vs *= (1.0f / 3.0f);
    float var = logf(sqrtf(vs) + 1.0f);

    float ue = 0.0f;
#pragma unroll
    for (int a = 0; a < 4; ++a) ue += W[((size_t)u << 2) + a] * xu[a + 1];

    base_o[ud] = base;
    ue_o[ud]   = ue;
    if (lane == 0) var_o[u] = var;
}

// One wave per batch element: X_post, X_var_user, AugUser, X_mean_user.
__global__ __launch_bounds__(256) void gather_k(
    const float* __restrict__ p0, const float* __restrict__ p1r0, const float* __restrict__ p2,
    const float* __restrict__ base, const float* __restrict__ var, const float* __restrict__ ue,
    const int* __restrict__ src_id, const int* __restrict__ rumer, float* __restrict__ out)
{
    int b    = blockIdx.x * 4 + (threadIdx.x >> 6);
    int lane = threadIdx.x & 63;

    int sp = src_id[b];
    size_t spd = ((size_t)sp << 6) + lane;
    out[((size_t)b << 6) + lane] = (p0[spd] + p1r0[spd] + p2[spd]) * (1.0f / 3.0f);

    float xv = 0.0f, xm = 0.0f, au = 0.0f;
    for (int h = 0; h < H_DIM; ++h) {
        int uu = rumer[b * H_DIM + h];
        size_t uud = ((size_t)uu << 6) + lane;
        float bv = base[uud];
        xv += var[uu] * bv;
        xm += bv;
        au += ue[uud];
    }
    out[((size_t)(B_DIM     + b) << 6) + lane] = xv;
    out[((size_t)(2 * B_DIM + b) << 6) + lane] = au * (1.0f / H_DIM);
    out[((size_t)(3 * B_DIM + b) << 6) + lane] = xm * (1.0f / H_DIM);
}

extern "C" void kernel_launch(void* const* d_in, const int* in_sizes, int n_in,
                              void* d_out, int out_size, void* d_ws, size_t ws_size,
                              hipStream_t stream)
{
    const float* u0 = (const float*)d_in[5];
    const float* p0 = (const float*)d_in[6];
    const float* W  = (const float*)d_in[7];
    const int* src   = (const int*)d_in[8];
    const int* rumer = (const int*)d_in[10];
    float* out = (float*)d_out;

    APtrs Ap;
    for (int r = 0; r < 5; ++r) Ap.p[r] = (const float*)d_in[r];

    // fp32 intermediates
    float* u1   = (float*)d_ws;                 // 5*U*64
    float* p1   = u1 + 5l * U_DIM * 64;         // 5*P*64
    float* p2   = p1 + 5l * P_DIM * 64;         // P*64
    float* u2   = p2 + (long)P_DIM * 64;        // 5*U*64
    float* base = u2 + 5l * U_DIM * 64;         // U*64
    float* var  = base + (long)U_DIM * 64;      // U
    float* ue   = var + U_DIM;                  // U*64

    // small bf16-transposed B operands, aliased into base/var/ue (<4.23 MB,
    // dead until user_stats_k).
    unsigned short* p0T = (unsigned short*)base;
    unsigned short* u0T = p0T + 64l * P_DIM;
    unsigned short* p1T = (unsigned short*)base;
    unsigned short* u1T = p1T + 5l * 64 * P_DIM;

    // bf16 A copies after the fp32 intermediates
    const size_t interm_floats = 7872512;              // through end of ue
    const size_t UP = (size_t)U_DIM * P_DIM;           // 33,554,432
    unsigned short* A_rm = (unsigned short*)((float*)d_ws + interm_floats);
    unsigned short* A_T  = A_rm + 5 * UP;
    const size_t need_B = interm_floats * 4 + 5 * UP * 2;            // 367,034,368
    const size_t need_A = need_B + 5 * UP * 2;                       // 702,578,688

    const size_t zero_bytes = (size_t)(5l * U_DIM * 64 + 5l * P_DIM * 64 +
                                       (long)P_DIM * 64 + 5l * U_DIM * 64) * sizeof(float);
    hipMemsetAsync(d_ws, 0, zero_bytes, stream);

    transpose_bf16_k<<<dim3(P_DIM / 64, 1), 256, 0, stream>>>(p0, p0T, P_DIM, 0, 0);
    transpose_bf16_k<<<dim3(U_DIM / 64, 1), 256, 0, stream>>>(u0, u0T, U_DIM, 0, 0);

    if (ws_size >= need_B) {
        const bool tierA = (ws_size >= need_A);
        conv_bf16_k<<<dim3(P_DIM / 64, U_DIM / 64, 5), 256, 0, stream>>>(
            Ap, A_rm, tierA ? A_T : (unsigned short*)nullptr);

        // u1[r] = A[r] @ p0
        gemm_bf16<false><<<dim3(64, 5, 8), 256, 0, stream>>>(
            A_rm, (long)UP, p0T, 0, u1, (long)U_DIM * 64, P_DIM, 512);
        // p1[r] = A[r]^T @ u0
        if (tierA)
            gemm_bf16<false><<<dim3(32, 5, 16), 256, 0, stream>>>(
                A_T, (long)UP, u0T, 0, p1, (long)P_DIM * 64, U_DIM, 512);
        else
            gemm_bf16<true><<<dim3(32, 5, 16), 256, 0, stream>>>(
                A_rm, (long)UP, u0T, 0, p1, (long)P_DIM * 64, U_DIM, 512);

        transpose_bf16_k<<<dim3(P_DIM / 64, 5), 256, 0, stream>>>(p1, p1T, P_DIM, (long)P_DIM * 64, 64l * P_DIM);
        transpose_bf16_k<<<dim3(U_DIM / 64, 1), 256, 0, stream>>>(u1, u1T, U_DIM, 0, 0);

        // u2[r] = A[r] @ p1[r]
        gemm_bf16<false><<<dim3(64, 5, 8), 256, 0, stream>>>(
            A_rm, (long)UP, p1T, 64l * P_DIM, u2, (long)U_DIM * 64, P_DIM, 512);
        // p2[0] = A[0]^T @ u1[0]
        if (tierA)
            gemm_bf16<false><<<dim3(32, 1, 32), 256, 0, stream>>>(
                A_T, 0, u1T, 0, p2, 0, U_DIM, 256);
        else
            gemm_bf16<true><<<dim3(32, 1, 32), 256, 0, stream>>>(
                A_rm, 0, u1T, 0, p2, 0, U_DIM, 256);
    } else {
        // Tier C: fp32 fallback (round-1 proven path)
        gemm_f32<false><<<dim3(64, 5, 4), 256, 0, stream>>>(Ap, p0T, u1, 0, (long)U_DIM * 64, 1024);
        gemm_f32<true ><<<dim3(32, 5, 8), 256, 0, stream>>>(Ap, u0T, p1, 0, (long)P_DIM * 64, 1024);
        transpose_bf16_k<<<dim3(P_DIM / 64, 5), 256, 0, stream>>>(p1, p1T, P_DIM, (long)P_DIM * 64, 64l * P_DIM);
        transpose_bf16_k<<<dim3(U_DIM / 64, 1), 256, 0, stream>>>(u1, u1T, U_DIM, 0, 0);
        gemm_f32<false><<<dim3(64, 5, 4), 256, 0, stream>>>(Ap, p1T, u2, 64l * P_DIM, (long)U_DIM * 64, 1024);
        gemm_f32<true ><<<dim3(32, 1, 32), 256, 0, stream>>>(Ap, u1T, p2, 0, 0, 256);
    }

    user_stats_k<<<U_DIM / 4, 256, 0, stream>>>(u0, u1, u2, W, base, var, ue);
    gather_k<<<B_DIM / 4, 256, 0, stream>>>(p0, p1, p2, base, var, ue, src, rumer, out);
}